// Round 3
// baseline (251.751 us; speedup 1.0000x reference)
//
#include <hip/hip_runtime.h>
#include <math.h>

constexpr int DIM = 64;
constexpr int S = 8;
constexpr int WPB = 4;                 // waves per block (256 threads)
constexpr int BLOCK = WPB * 64;
constexpr int QPB = 16;                // queries per block-iteration (one full MFMA A-tile)
constexpr int GRID = 1024;             // 4 blocks/CU x 256 CU, grid-stride over batch

typedef __attribute__((ext_vector_type(8))) __bf16 bf16x8;   // 4 VGPRs: MFMA A/B frag
typedef __attribute__((ext_vector_type(4))) float  f32x4;    // MFMA C/D frag

// DPP quad-perm lane exchange (VALU pipe, not DS) — correctness verified R3-R6
template <int CTRL>
__device__ __forceinline__ float dppx(float x) {
    return __builtin_bit_cast(float,
        __builtin_amdgcn_mov_dpp(__builtin_bit_cast(int, x), CTRL, 0xf, 0xf, true));
}
#define XOR1 0xB1   // quad_perm(1,0,3,2)  == shfl_xor 1
#define XOR2 0x4E   // quad_perm(2,3,0,1)  == shfl_xor 2

// pack two floats as bf16 (RNE-ish) into one dword: lo=a, hi=b
__device__ __forceinline__ unsigned pk_bf16(float a, float b) {
    unsigned ua = __builtin_bit_cast(unsigned, a);
    unsigned ub = __builtin_bit_cast(unsigned, b);
    ua = (ua + 0x8000u) >> 16;
    ub = (ub + 0x8000u) & 0xffff0000u;
    return ua | ub;
}

// 8-way softmax over lanes' (lane&7) scores; broadcasts w[0..7] to all lanes.
__device__ __forceinline__ void octet_softmax(float sc, float* wout) {
    float m = sc;
    m = fmaxf(m, dppx<XOR1>(m));
    m = fmaxf(m, dppx<XOR2>(m));
    m = fmaxf(m, __shfl_xor(m, 4));
    float e = __expf(sc - m);
    float s = e;
    s += dppx<XOR1>(s);
    s += dppx<XOR2>(s);
    s += __shfl_xor(s, 4);
    float w = e / s;
    #pragma unroll
    for (int k = 0; k < 8; k++) wout[k] = __shfl(w, k);   // lane k (mod 8) holds s=k
}

__global__ __launch_bounds__(BLOCK, 4)
void sestkgcn_kernel(
    const int*   __restrict__ u_idx,
    const int*   __restrict__ v_idx,
    const float* __restrict__ usr_feat,
    const float* __restrict__ item_feat,
    const float* __restrict__ rel_feat,
    const int*   __restrict__ neigh_uu,
    const float* __restrict__ neigh_uu_st,
    const int*   __restrict__ neigh_ui,
    const float* __restrict__ neigh_ui_rat,
    const float* __restrict__ neigh_ui_vot,
    const float* __restrict__ neigh_ui_tim,
    const int*   __restrict__ neigh_iu,
    const float* __restrict__ neigh_iu_rat,
    const float* __restrict__ neigh_iu_vot,
    const float* __restrict__ neigh_iu_tim,
    const int*   __restrict__ neigh_ii,
    const int*   __restrict__ neigh_ir,
    const float* __restrict__ Wu,
    const float* __restrict__ bu,
    const float* __restrict__ Wv,
    const float* __restrict__ bv,
    float*       __restrict__ out,
    int n)
{
    // B-fragment layout for mfma_f32_16x16x32_bf16, frag f = kt*4+nt:
    //   sBF[(f*64 + lane)*4 + d] packs W[32*kt + 8*(lane>>4) + 2d][16*nt + (lane&15)] (lo)
    //   and row+1 (hi) — element j of the lane's 8 bf16 is k = 32*kt + 8*(lane>>4) + j.
    __shared__ unsigned sBFu[2048];
    __shared__ unsigned sBFv[2048];
    // 16 queries' x vectors, bf16 hi + residual lo, per side. Short index
    // q*64 + (d ^ ((q&7)<<3)) — XOR swizzle keeps the A-frag ds_read_b128
    // conflict-free (8 distinct 16B slots per lane octet).
    __shared__ __align__(16) unsigned short sXuh[QPB * 64];
    __shared__ __align__(16) unsigned short sXul[QPB * 64];
    __shared__ __align__(16) unsigned short sXvh[QPB * 64];
    __shared__ __align__(16) unsigned short sXvl[QPB * 64];
    // per-wave partial dot products: sP[wave][q]
    __shared__ __align__(16) float sP[WPB][QPB];

    const int tid = threadIdx.x;
    for (int i = tid; i < 2048; i += BLOCK) {
        const int d = i & 3, l = (i >> 2) & 63, f = i >> 8;
        const int row = ((f >> 2) << 5) + ((l >> 4) << 3) + (d << 1);
        const int col = ((f & 3) << 4) + (l & 15);
        sBFu[i] = pk_bf16(Wu[row * DIM + col], Wu[(row + 1) * DIM + col]);
        sBFv[i] = pk_bf16(Wv[row * DIM + col], Wv[(row + 1) * DIM + col]);
    }
    __syncthreads();

    const int wave = tid >> 6;
    const int lane = tid & 63;
    const int ls   = lane & 7;

    // ---- phase-2 addressing (constant per thread) ----
    const int qa = lane & 15;          // A row = query index (matches C/D row group)
    const int ga = lane >> 4;          // k-chunk group
    const int asz = (qa & 7) << 3;
    const int a0 = qa * 64 + ((ga * 8) ^ asz);         // kt0 A-frag (short index)
    const int a1 = qa * 64 + (((32 + ga * 8)) ^ asz);  // kt1 (XOR closed on bits 3-5)
    const unsigned* bfu0 = &sBFu[(0 + wave) * 256 + lane * 4];  // kt0, nt=wave
    const unsigned* bfu1 = &sBFu[(4 + wave) * 256 + lane * 4];  // kt1, nt=wave
    const unsigned* bfv0 = &sBFv[(0 + wave) * 256 + lane * 4];
    const unsigned* bfv1 = &sBFv[(4 + wave) * 256 + lane * 4];
    const float bu_w = bu[wave * 16 + qa];   // bias for output dim 16*wave + col
    const float bv_w = bv[wave * 16 + qa];

    const int bstep = GRID * QPB;
    int b_base = blockIdx.x * QPB;
    int b = b_base + 4 * wave;               // this wave's first query
    int u, v;
    {
        const int bc = (b < n) ? b : (n - 1);
        u = u_idx[bc];
        v = v_idx[bc];
    }

    while (b_base < n) {
        // ================= phase 1: 4 queries -> x vectors in sX =================
        #pragma unroll 1
        for (int j = 0; j < 4; j++) {
            const int b_next = (j < 3) ? (b + 1) : (b_base + bstep + 4 * wave);
            const int bnc = (b_next < n) ? b_next : (n - 1);
            const int u_nxt = u_idx[bnc];
            const int v_nxt = v_idx[bnc];

            const unsigned u8 = (unsigned)u << 3, v8 = (unsigned)v << 3;

            const float u_d = usr_feat[((unsigned)u << 6) | (unsigned)lane];
            const float v_d = item_feat[((unsigned)v << 6) | (unsigned)lane];

            const float sc_uu = neigh_uu_st[u8 + ls];
            const float sc_ui = neigh_ui_rat[u8 + ls] * neigh_ui_vot[u8 + ls] * neigh_ui_tim[u8 + ls];
            const float sc_iu = neigh_iu_rat[v8 + ls] * neigh_iu_vot[v8 + ls] * neigh_iu_tim[v8 + ls];

            // ---- user side ----
            float w[S];
            octet_softmax(sc_uu, w);
            float agg_uu = 0.f;
            {
                const int4 i0 = ((const int4*)(neigh_uu + u8))[0];
                const int4 i1 = ((const int4*)(neigh_uu + u8))[1];
                const int ni[S] = {i0.x, i0.y, i0.z, i0.w, i1.x, i1.y, i1.z, i1.w};
                float r[S];
                #pragma unroll
                for (int s = 0; s < S; s++) r[s] = usr_feat[((unsigned)ni[s] << 6) | (unsigned)lane];
                #pragma unroll
                for (int s = 0; s < S; s++) agg_uu = fmaf(w[s], r[s], agg_uu);
            }

            octet_softmax(sc_ui, w);
            float agg_ui = 0.f;
            {
                const int4 i0 = ((const int4*)(neigh_ui + u8))[0];
                const int4 i1 = ((const int4*)(neigh_ui + u8))[1];
                const int ni[S] = {i0.x, i0.y, i0.z, i0.w, i1.x, i1.y, i1.z, i1.w};
                float r[S];
                #pragma unroll
                for (int s = 0; s < S; s++) r[s] = item_feat[((unsigned)ni[s] << 6) | (unsigned)lane];
                #pragma unroll
                for (int s = 0; s < S; s++) agg_ui = fmaf(w[s], r[s], agg_ui);
            }

            // ---- item side ----
            octet_softmax(sc_iu, w);
            float agg_iu = 0.f;
            {
                const int4 i0 = ((const int4*)(neigh_iu + v8))[0];
                const int4 i1 = ((const int4*)(neigh_iu + v8))[1];
                const int ni[S] = {i0.x, i0.y, i0.z, i0.w, i1.x, i1.y, i1.z, i1.w};
                float r[S];
                #pragma unroll
                for (int s = 0; s < S; s++) r[s] = usr_feat[((unsigned)ni[s] << 6) | (unsigned)lane];
                #pragma unroll
                for (int s = 0; s < S; s++) agg_iu = fmaf(w[s], r[s], agg_iu);
            }

            // KG attention: merge 8 dot-products so lane holds total for s=lane&7
            {
                const int4 r0 = ((const int4*)(neigh_ir + v8))[0];
                const int4 r1 = ((const int4*)(neigh_ir + v8))[1];
                const int nr[S] = {r0.x, r0.y, r0.z, r0.w, r1.x, r1.y, r1.z, r1.w};
                float p[S];
                #pragma unroll
                for (int s = 0; s < S; s++) p[s] = u_d * rel_feat[((unsigned)nr[s] << 6) | (unsigned)lane];

                float m1[4];
                #pragma unroll
                for (int i = 0; i < 4; i++) {
                    float lo = (lane & 1) ? p[2 * i + 1] : p[2 * i];
                    float hi = (lane & 1) ? p[2 * i]     : p[2 * i + 1];
                    m1[i] = lo + dppx<XOR1>(hi);
                }
                float m2[2];
                #pragma unroll
                for (int i = 0; i < 2; i++) {
                    float lo = (lane & 2) ? m1[2 * i + 1] : m1[2 * i];
                    float hi = (lane & 2) ? m1[2 * i]     : m1[2 * i + 1];
                    m2[i] = lo + dppx<XOR2>(hi);
                }
                float lo = (lane & 4) ? m2[1] : m2[0];
                float hi = (lane & 4) ? m2[0] : m2[1];
                float att = lo + __shfl_xor(hi, 4);
                att += __shfl_xor(att, 8);
                att += __shfl_xor(att, 16);
                att += __shfl_xor(att, 32);
                octet_softmax(att, w);
            }
            float agg_ii = 0.f;
            {
                const int4 i0 = ((const int4*)(neigh_ii + v8))[0];
                const int4 i1 = ((const int4*)(neigh_ii + v8))[1];
                const int ni[S] = {i0.x, i0.y, i0.z, i0.w, i1.x, i1.y, i1.z, i1.w};
                float r[S];
                #pragma unroll
                for (int s = 0; s < S; s++) r[s] = item_feat[((unsigned)ni[s] << 6) | (unsigned)lane];
                #pragma unroll
                for (int s = 0; s < S; s++) agg_ii = fmaf(w[s], r[s], agg_ii);
            }

            // ---- stage x = emb + aggs as bf16 hi + residual lo (swizzled) ----
            const float xu = u_d + agg_uu + agg_ui;
            const float xv = v_d + agg_iu + agg_ii;
            const int ql = 4 * wave + j;
            const int widx = ql * 64 + (lane ^ ((ql & 7) << 3));
            {
                const unsigned xb = __builtin_bit_cast(unsigned, xu);
                const unsigned hb = (xb + 0x8000u) & 0xffff0000u;
                const float xl = xu - __builtin_bit_cast(float, hb);
                sXuh[widx] = (unsigned short)(hb >> 16);
                sXul[widx] = (unsigned short)((__builtin_bit_cast(unsigned, xl) + 0x8000u) >> 16);
            }
            {
                const unsigned xb = __builtin_bit_cast(unsigned, xv);
                const unsigned hb = (xb + 0x8000u) & 0xffff0000u;
                const float xl = xv - __builtin_bit_cast(float, hb);
                sXvh[widx] = (unsigned short)(hb >> 16);
                sXvl[widx] = (unsigned short)((__builtin_bit_cast(unsigned, xl) + 0x8000u) >> 16);
            }

            b = b_next;
            u = u_nxt;
            v = v_nxt;
        }
        __syncthreads();   // B1: all 16 x vectors staged

        // ========== phase 2: batched 16-query matvec pair, wave owns nt=wave ==========
        {
            const bf16x8 Auh0 = *(const bf16x8*)&sXuh[a0];
            const bf16x8 Aul0 = *(const bf16x8*)&sXul[a0];
            const bf16x8 Auh1 = *(const bf16x8*)&sXuh[a1];
            const bf16x8 Aul1 = *(const bf16x8*)&sXul[a1];
            const bf16x8 Avh0 = *(const bf16x8*)&sXvh[a0];
            const bf16x8 Avl0 = *(const bf16x8*)&sXvl[a0];
            const bf16x8 Avh1 = *(const bf16x8*)&sXvh[a1];
            const bf16x8 Avl1 = *(const bf16x8*)&sXvl[a1];
            const bf16x8 Bu0 = *(const bf16x8*)bfu0;
            const bf16x8 Bu1 = *(const bf16x8*)bfu1;
            const bf16x8 Bv0 = *(const bf16x8*)bfv0;
            const bf16x8 Bv1 = *(const bf16x8*)bfv1;

            f32x4 au = {0.f, 0.f, 0.f, 0.f};
            f32x4 av = {0.f, 0.f, 0.f, 0.f};
            au = __builtin_amdgcn_mfma_f32_16x16x32_bf16(Auh0, Bu0, au, 0, 0, 0);
            au = __builtin_amdgcn_mfma_f32_16x16x32_bf16(Aul0, Bu0, au, 0, 0, 0);
            au = __builtin_amdgcn_mfma_f32_16x16x32_bf16(Auh1, Bu1, au, 0, 0, 0);
            au = __builtin_amdgcn_mfma_f32_16x16x32_bf16(Aul1, Bu1, au, 0, 0, 0);
            av = __builtin_amdgcn_mfma_f32_16x16x32_bf16(Avh0, Bv0, av, 0, 0, 0);
            av = __builtin_amdgcn_mfma_f32_16x16x32_bf16(Avl0, Bv0, av, 0, 0, 0);
            av = __builtin_amdgcn_mfma_f32_16x16x32_bf16(Avh1, Bv1, av, 0, 0, 0);
            av = __builtin_amdgcn_mfma_f32_16x16x32_bf16(Avl1, Bv1, av, 0, 0, 0);

            // C layout: col = lane&15 (= output dim within tile), row = 4*ga + reg = query.
            // Per reg: relu+bias both sides, partial dot over this wave's 16 dims.
            float pr[4];
            #pragma unroll
            for (int r = 0; r < 4; r++) {
                const float hu = fmaxf(au[r] + bu_w, 0.f);
                const float hv = fmaxf(av[r] + bv_w, 0.f);
                float p = hu * hv;
                p += dppx<XOR1>(p);
                p += dppx<XOR2>(p);
                p += __shfl_xor(p, 4);
                p += __shfl_xor(p, 8);
                pr[r] = p;
            }
            if ((lane & 15) == 0) {
                *(float4*)&sP[wave][ga * 4] = make_float4(pr[0], pr[1], pr[2], pr[3]);
            }
        }
        __syncthreads();   // B2: partial dots staged

        // ========== phase 3: combine d-slices, sigmoid, store ==========
        if (tid < QPB) {
            const float p = sP[0][tid] + sP[1][tid] + sP[2][tid] + sP[3][tid];
            const int bq = b_base + tid;
            if (bq < n) out[bq] = 5.0f / (1.0f + __expf(-p));
        }
        // next phase-1 sX writes are safe: phase-2 sX reads completed before B2;
        // next sP writes are safe: they occur after next B1, which waits for phase 3.

        b_base += bstep;
    }
}

extern "C" void kernel_launch(void* const* d_in, const int* in_sizes, int n_in,
                              void* d_out, int out_size, void* d_ws, size_t ws_size,
                              hipStream_t stream) {
    const int*   u_idx        = (const int*)  d_in[0];
    const int*   v_idx        = (const int*)  d_in[1];
    const float* usr_feat     = (const float*)d_in[2];
    const float* item_feat    = (const float*)d_in[3];
    const float* rel_feat     = (const float*)d_in[4];
    const int*   neigh_uu     = (const int*)  d_in[5];
    const float* neigh_uu_st  = (const float*)d_in[6];
    const int*   neigh_ui     = (const int*)  d_in[7];
    const float* neigh_ui_rat = (const float*)d_in[8];
    const float* neigh_ui_vot = (const float*)d_in[9];
    const float* neigh_ui_tim = (const float*)d_in[10];
    const int*   neigh_iu     = (const int*)  d_in[11];
    const float* neigh_iu_rat = (const float*)d_in[12];
    const float* neigh_iu_vot = (const float*)d_in[13];
    const float* neigh_iu_tim = (const float*)d_in[14];
    const int*   neigh_ii     = (const int*)  d_in[15];
    const int*   neigh_ir     = (const int*)  d_in[16];
    const float* Wu           = (const float*)d_in[17];
    const float* bu           = (const float*)d_in[18];
    const float* Wv           = (const float*)d_in[19];
    const float* bv           = (const float*)d_in[20];
    float*       out          = (float*)d_out;

    const int n = in_sizes[0];
    int blocks = (n + QPB - 1) / QPB;
    if (blocks > GRID) blocks = GRID;
    sestkgcn_kernel<<<blocks, BLOCK, 0, stream>>>(
        u_idx, v_idx, usr_feat, item_feat, rel_feat,
        neigh_uu, neigh_uu_st, neigh_ui, neigh_ui_rat, neigh_ui_vot, neigh_ui_tim,
        neigh_iu, neigh_iu_rat, neigh_iu_vot, neigh_iu_tim, neigh_ii, neigh_ir,
        Wu, bu, Wv, bv, out, n);
}